// Round 3
// baseline (506.560 us; speedup 1.0000x reference)
//
#include <hip/hip_runtime.h>

#define H 512
#define W 960
#define OH 508
#define OW 956
#define NIMG 48

#define RH 32                       // output rows per wave (RH=16 halo tax proved unpaid-for)
#define WAVES_PER_BLOCK 4
#define ROWS_PER_BLOCK (RH * WAVES_PER_BLOCK)   // 128
#define CW 4                        // output cols per thread
#define STRIPW (64 * CW)            // 256 output cols per wave-strip
#define KMAX (RH + 4)               // 36 — COMPILE-TIME trip count (pad + guard stores)

typedef float f32x4 __attribute__((ext_vector_type(4)));

__device__ __forceinline__ void load_row(const float* __restrict__ xi,
                                         const float* __restrict__ yi,
                                         int r, int cbl,
                                         float xd[8], float yd[8])
{
    const int rl = r < H ? r : (H - 1);   // clamp (bottom pad rows / prefetch overrun)
    const float4* px = (const float4*)(xi + (size_t)rl * W + cbl);
    const float4* py = (const float4*)(yi + (size_t)rl * W + cbl);
    float4 xa = px[0], xb = px[1];
    float4 ya = py[0], yb = py[1];
    xd[0] = xa.x; xd[1] = xa.y; xd[2] = xa.z; xd[3] = xa.w;
    xd[4] = xb.x; xd[5] = xb.y; xd[6] = xb.z; xd[7] = xb.w;
    yd[0] = ya.x; yd[1] = ya.y; yd[2] = ya.z; yd[3] = ya.w;
    yd[4] = yb.x; yd[5] = yb.y; yd[6] = yb.z; yd[7] = yb.w;
}

// Fully register-resident sliding-window SSIM.
// Thread = 4 output columns; wave = 256-col strip x 32 rows; no LDS, no barriers.
// Round-2 structure: constant trip count + unroll 4 (kills rotation movs),
// 1-deep load pipeline (row k+1 in flight under row k's compute), fast rcp.
__global__ __launch_bounds__(256, 4) void ssim_kernel(
    const float* __restrict__ x, const float* __restrict__ y,
    float* __restrict__ out)
{
    const int img  = blockIdx.z;
    const int lane = threadIdx.x;                       // 0..63
    const int wv   = threadIdx.y;                       // 0..3
    const int c0   = blockIdx.x * STRIPW;               // 0,256,512,768
    const int h0   = blockIdx.y * ROWS_PER_BLOCK + wv * RH;   // 0..480

    const int cb = c0 + lane * CW;                      // output col base
    const bool col_ok = (cb + CW - 1) < OW;             // cb <= 952
    const int cbl = col_ok ? cb : (OW - CW);            // clamped load base (952)

    const float* __restrict__ xi = x + (size_t)img * H * W;
    const float* __restrict__ yi = y + (size_t)img * H * W;
    float* __restrict__ oi = out + (size_t)img * OH * OW;

    // register pipeline state
    float xm1[6], ym1[6];           // prev input row, cols cbl+1..cbl+6 (centers)
    float hxa[6], hxb[6];           // horiz 3-sums of x at rows r-2, r-1
    float hya[6], hyb[6];
    float muxB[6], muyB[6];         // mu at stage-1 row p-1
    float haA[4], haB[4];           // horiz 3-sums of a at stage-1 rows p-2, p-1
    float hbA[4], hbB[4];
    float hcA[4], hcB[4];

    const float inv9 = 1.0f / 9.0f;
    const float C1v = 1e-4f, C2v = 9e-4f;

    // 1-deep software pipeline: cur = row k, nxt = row k+1 (in flight)
    float xcur[8], ycur[8], xnxt[8], ynxt[8];
    load_row(xi, yi, h0, cbl, xcur, ycur);

#pragma unroll 4
    for (int k = 0; k < KMAX; ++k) {
        // issue next row's loads first — they stay in flight under this
        // iteration's ~180-instr compute chain (per-wave MLP, not TLP)
        load_row(xi, yi, h0 + k + 1, cbl, xnxt, ynxt);

        const int r = h0 + k;

        // horizontal 3-sums of this input row
        float hx[6], hy[6];
#pragma unroll
        for (int q = 0; q < 6; ++q) {
            hx[q] = xcur[q] + xcur[q + 1] + xcur[q + 2];
            hy[q] = ycur[q] + ycur[q + 1] + ycur[q + 2];
        }

        if (k >= 2) {
            // stage-1 row p = r-2
            float mux[6], muy[6];
            float a6[6], b6[6], c6[6];
#pragma unroll
            for (int q = 0; q < 6; ++q) {
                mux[q] = (hxa[q] + hxb[q] + hx[q]) * inv9;
                muy[q] = (hya[q] + hyb[q] + hy[q]) * inv9;
                float dx = xm1[q] - mux[q];   // x(r-1, cb+q+1)
                float dy = ym1[q] - muy[q];
                a6[q] = dx * dx;
                b6[q] = dy * dy;
                c6[q] = dx * dy;
            }
            float ha[4], hb[4], hc[4];
#pragma unroll
            for (int w = 0; w < 4; ++w) {
                ha[w] = a6[w] + a6[w + 1] + a6[w + 2];
                hb[w] = b6[w] + b6[w + 1] + b6[w + 2];
                hc[w] = c6[w] + c6[w + 1] + c6[w + 2];
            }

            if (k >= 4) {
                // output row h = p - 2 = r - 4
                const int h = r - 4;
                float ov[4];
#pragma unroll
                for (int w = 0; w < 4; ++w) {
                    float sigx  = (haA[w] + haB[w] + ha[w]) * inv9;
                    float sigy  = (hbA[w] + hbB[w] + hb[w]) * inv9;
                    float sigxy = (hcA[w] + hcB[w] + hc[w]) * inv9;
                    float mx = muxB[w + 1];   // mu at stage-1 row p-1, col cb+w+1
                    float my = muyB[w + 1];
                    float n = (2.f * mx * my + C1v) * (2.f * sigxy + C2v);
                    float d = (mx * mx + my * my + C1v) * (sigx + sigy + C2v);
                    // d >= C1*C2 > 0; fast rcp (~1e-7 rel err) vs 0.0078 tolerance
                    float v = 1.f - n * __builtin_amdgcn_rcpf(d);
                    ov[w] = fminf(fmaxf(v, 0.f), 2.f);
                }
                if (col_ok && h < OH) {   // h<OH: bottom-pad guard (wave-uniform)
                    // output never re-read: NT store keeps L2/L3 for inputs
                    f32x4 o = {ov[0], ov[1], ov[2], ov[3]};
                    __builtin_nontemporal_store(o, (f32x4*)(oi + (size_t)h * OW + cb));
                }
            }

            // rotate stage-2 histories (renamed away under unroll)
#pragma unroll
            for (int w = 0; w < 4; ++w) {
                haA[w] = haB[w]; haB[w] = ha[w];
                hbA[w] = hbB[w]; hbB[w] = hb[w];
                hcA[w] = hcB[w]; hcB[w] = hc[w];
            }
#pragma unroll
            for (int q = 0; q < 6; ++q) {
                muxB[q] = mux[q];
                muyB[q] = muy[q];
            }
        }

        // rotate stage-1 histories (renamed away under unroll)
#pragma unroll
        for (int q = 0; q < 6; ++q) {
            hxa[q] = hxb[q]; hxb[q] = hx[q];
            hya[q] = hyb[q]; hyb[q] = hy[q];
            xm1[q] = xcur[q + 1];
            ym1[q] = ycur[q + 1];
        }
        // advance load pipeline (renamed away under unroll)
#pragma unroll
        for (int i = 0; i < 8; ++i) {
            xcur[i] = xnxt[i];
            ycur[i] = ynxt[i];
        }
    }
}

extern "C" void kernel_launch(void* const* d_in, const int* in_sizes, int n_in,
                              void* d_out, int out_size, void* d_ws, size_t ws_size,
                              hipStream_t stream) {
    const float* x = (const float*)d_in[0];
    const float* y = (const float*)d_in[1];
    float* out = (float*)d_out;

    dim3 grid((OW + STRIPW - 1) / STRIPW,                 // 4
              (OH + ROWS_PER_BLOCK - 1) / ROWS_PER_BLOCK, // 4
              NIMG);                                      // 48
    dim3 block(64, WAVES_PER_BLOCK, 1);
    ssim_kernel<<<grid, block, 0, stream>>>(x, y, out);
}

// Round 4
// 250.177 us; speedup vs baseline: 2.0248x; 2.0248x over previous
//
#include <hip/hip_runtime.h>

#define H 512
#define W 960
#define OH 508
#define OW 956
#define NIMG 48

#define RH 32                       // output rows per wave
#define WAVES_PER_BLOCK 4
#define ROWS_PER_BLOCK (RH * WAVES_PER_BLOCK)   // 128
#define CW 4                        // output cols per thread
#define STRIPW (64 * CW)            // 256 output cols per wave-strip
#define KK 12                       // 12 x 3-phase body = 36 input rows (compile-time)

typedef float f32x4 __attribute__((ext_vector_type(4)));

// One pipeline phase: stream input row (wave-local index KV), update histories.
// ALL array args are distinct named locals with compile-time indices only —
// rotation is SSA renaming, nothing can fall to scratch (round-3 lesson:
// SROA demoted the function-call/partial-unroll version wholesale; WRITE_SIZE
// 92->639MB at VGPR=64 is the demotion signature).
//   HX2/HX1 = horiz 3-sums rows k-2,k-1 ; HXW = dest for row k
//   XC1 = centers of row k-1 ; XCW = dest centers row k
//   HA2/HA1 = horiz 3-sums of a at center rows k-3,k-2 ; HAW = dest (row k-1)
//   MIX = mu at center row k-2 (for output) ; MOX = dest mu (row k-1)
#define PHASE(KV, HX2,HY2, HX1,HY1, HXW,HYW, XC1,YC1, XCW,YCW, \
              HA2,HB2,HC2, HA1,HB1,HC1, HAW,HBW,HCW, MIX,MIY, MOX,MOY) \
{ \
    const int k_ = (KV); \
    const int r_ = h0 + k_; \
    const int rl_ = r_ < H ? r_ : (H - 1); \
    const float4* px_ = (const float4*)(xi + (size_t)rl_ * W + cbl); \
    const float4* py_ = (const float4*)(yi + (size_t)rl_ * W + cbl); \
    float4 xa_ = px_[0], xb_ = px_[1]; \
    float4 ya_ = py_[0], yb_ = py_[1]; \
    float xc_[8] = {xa_.x, xa_.y, xa_.z, xa_.w, xb_.x, xb_.y, xb_.z, xb_.w}; \
    float yc_[8] = {ya_.x, ya_.y, ya_.z, ya_.w, yb_.x, yb_.y, yb_.z, yb_.w}; \
    _Pragma("unroll") \
    for (int q = 0; q < 6; ++q) { \
        HXW[q] = xc_[q] + xc_[q + 1] + xc_[q + 2]; \
        HYW[q] = yc_[q] + yc_[q + 1] + yc_[q + 2]; \
        XCW[q] = xc_[q + 1]; \
        YCW[q] = yc_[q + 1]; \
    } \
    if (k_ >= 2) { \
        float a6_[6], b6_[6], c6_[6]; \
        _Pragma("unroll") \
        for (int q = 0; q < 6; ++q) { \
            MOX[q] = (HX2[q] + HX1[q] + HXW[q]) * inv9; \
            MOY[q] = (HY2[q] + HY1[q] + HYW[q]) * inv9; \
            float dx_ = XC1[q] - MOX[q]; \
            float dy_ = YC1[q] - MOY[q]; \
            a6_[q] = dx_ * dx_; \
            b6_[q] = dy_ * dy_; \
            c6_[q] = dx_ * dy_; \
        } \
        float ha_[4], hb_[4], hc_[4]; \
        _Pragma("unroll") \
        for (int w = 0; w < 4; ++w) { \
            ha_[w] = a6_[w] + a6_[w + 1] + a6_[w + 2]; \
            hb_[w] = b6_[w] + b6_[w + 1] + b6_[w + 2]; \
            hc_[w] = c6_[w] + c6_[w + 1] + c6_[w + 2]; \
        } \
        if (k_ >= 4) { \
            const int h_ = h0 + k_ - 4; \
            float ov_[4]; \
            _Pragma("unroll") \
            for (int w = 0; w < 4; ++w) { \
                float sigx_  = (HA2[w] + HA1[w] + ha_[w]) * inv9; \
                float sigy_  = (HB2[w] + HB1[w] + hb_[w]) * inv9; \
                float sigxy_ = (HC2[w] + HC1[w] + hc_[w]) * inv9; \
                float mx_ = MIX[w + 1]; \
                float my_ = MIY[w + 1]; \
                float n_ = (2.f * mx_ * my_ + C1v) * (2.f * sigxy_ + C2v); \
                float d_ = (mx_ * mx_ + my_ * my_ + C1v) * (sigx_ + sigy_ + C2v); \
                float v_ = 1.f - n_ * __builtin_amdgcn_rcpf(d_); \
                ov_[w] = fminf(fmaxf(v_, 0.f), 2.f); \
            } \
            if (col_ok && h_ < OH) { \
                f32x4 o_ = {ov_[0], ov_[1], ov_[2], ov_[3]}; \
                __builtin_nontemporal_store(o_, (f32x4*)(oi + (size_t)h_ * OW + cb)); \
            } \
        } \
        _Pragma("unroll") \
        for (int w = 0; w < 4; ++w) { \
            HAW[w] = ha_[w]; HBW[w] = hb_[w]; HCW[w] = hc_[w]; \
        } \
    } \
}

// Register-resident sliding-window SSIM, 3-phase hand-rotated pipeline.
// Thread = 4 output cols; wave = 256-col strip x 32 rows; no LDS, no barriers.
__global__ __launch_bounds__(256) void ssim_kernel(
    const float* __restrict__ x, const float* __restrict__ y,
    float* __restrict__ out)
{
    const int img  = blockIdx.z;
    const int lane = threadIdx.x;                       // 0..63
    const int wv   = threadIdx.y;                       // 0..3
    const int c0   = blockIdx.x * STRIPW;               // 0,256,512,768
    const int h0   = blockIdx.y * ROWS_PER_BLOCK + wv * RH;   // 0..480

    const int cb = c0 + lane * CW;                      // output col base
    const bool col_ok = (cb + CW - 1) < OW;             // cb <= 952
    const int cbl = col_ok ? cb : (OW - CW);            // clamped load base (952)

    const float* __restrict__ xi = x + (size_t)img * H * W;
    const float* __restrict__ yi = y + (size_t)img * H * W;
    float* __restrict__ oi = out + (size_t)img * OH * OW;

    const float inv9 = 1.0f / 9.0f;
    const float C1v = 1e-4f, C2v = 9e-4f;

    // loop-carried state at body entry (about to process rows 3kk..3kk+2):
    //   hx_m1 = hx(3kk-1), hx_m2 = hx(3kk-2)
    //   xc_m1 = centers(3kk-1)
    //   ha_m1 = ha(3kk-2), ha_m2 = ha(3kk-3)
    //   mu_m  = mu(3kk-2)
    // kk=0 entries are uninitialized but unread (k>=2 / k>=4 guards).
    float hx_m2[6], hx_m1[6], hy_m2[6], hy_m1[6];
    float xc_m1[6], yc_m1[6];
    float ha_m2[4], ha_m1[4], hb_m2[4], hb_m1[4], hc_m2[4], hc_m1[4];
    float mu_mx[6], mu_my[6];

#pragma unroll 1
    for (int kk = 0; kk < KK; ++kk) {
        const int kb = 3 * kk;
        float hx0[6], hy0[6], hx1[6], hy1[6], hx2[6], hy2[6];
        float xc0[6], yc0[6], xc1[6], yc1[6], xc2[6], yc2[6];
        float ha0[4], hb0[4], hc0[4], ha1[4], hb1[4], hc1[4], ha2[4], hb2[4], hc2[4];
        float mu0x[6], mu0y[6], mu1x[6], mu1y[6], mu2x[6], mu2y[6];

        PHASE(kb + 0, hx_m2,hy_m2, hx_m1,hy_m1, hx0,hy0, xc_m1,yc_m1, xc0,yc0,
              ha_m2,hb_m2,hc_m2, ha_m1,hb_m1,hc_m1, ha0,hb0,hc0,
              mu_mx,mu_my, mu0x,mu0y)
        PHASE(kb + 1, hx_m1,hy_m1, hx0,hy0, hx1,hy1, xc0,yc0, xc1,yc1,
              ha_m1,hb_m1,hc_m1, ha0,hb0,hc0, ha1,hb1,hc1,
              mu0x,mu0y, mu1x,mu1y)
        PHASE(kb + 2, hx0,hy0, hx1,hy1, hx2,hy2, xc1,yc1, xc2,yc2,
              ha0,hb0,hc0, ha1,hb1,hc1, ha2,hb2,hc2,
              mu1x,mu1y, mu2x,mu2y)

        // carry to next body (coalescable phis — compile-time indices only)
#pragma unroll
        for (int q = 0; q < 6; ++q) {
            hx_m2[q] = hx1[q]; hx_m1[q] = hx2[q];
            hy_m2[q] = hy1[q]; hy_m1[q] = hy2[q];
            xc_m1[q] = xc2[q]; yc_m1[q] = yc2[q];
            mu_mx[q] = mu2x[q]; mu_my[q] = mu2y[q];
        }
#pragma unroll
        for (int w = 0; w < 4; ++w) {
            ha_m2[w] = ha1[w]; ha_m1[w] = ha2[w];
            hb_m2[w] = hb1[w]; hb_m1[w] = hb2[w];
            hc_m2[w] = hc1[w]; hc_m1[w] = hc2[w];
        }
    }
}

extern "C" void kernel_launch(void* const* d_in, const int* in_sizes, int n_in,
                              void* d_out, int out_size, void* d_ws, size_t ws_size,
                              hipStream_t stream) {
    const float* x = (const float*)d_in[0];
    const float* y = (const float*)d_in[1];
    float* out = (float*)d_out;

    dim3 grid((OW + STRIPW - 1) / STRIPW,                 // 4
              (OH + ROWS_PER_BLOCK - 1) / ROWS_PER_BLOCK, // 4
              NIMG);                                      // 48
    dim3 block(64, WAVES_PER_BLOCK, 1);
    ssim_kernel<<<grid, block, 0, stream>>>(x, y, out);
}